// Round 8
// baseline (265.703 us; speedup 1.0000x reference)
//
#include <hip/hip_runtime.h>

// ---------------------------------------------------------------------------
// MultiHeadAttention forward, MI355X/gfx950.
// B=2, T=2048, D=2048, H=16, Dh=128. fp32 in/out, bf16 MFMA internally.
// Reference quirks (faithful): multiplicative tril mask (masked scores = 0,
// NOT -inf -> exp(0)=1 contributions over ALL 2048 cols), scale = 1/sqrt(T).
// Round 8: QKV GEMM -> ring-3 depth-2 prefetch, ONE barrier + counted
// vmcnt(6) per K-tile (BM=128 BN=256 BK=64, 8 waves 64x64, 144KB LDS,
// grid 768 = 3 exact CU rounds). No intra-tile barriers: free-running waves
// overlap LDS reads with MFMA. Wo + attn unchanged (passing).
// ---------------------------------------------------------------------------

typedef __attribute__((ext_vector_type(4))) float  f32x4;
typedef __attribute__((ext_vector_type(8))) short  bf16x8;
typedef __attribute__((ext_vector_type(4))) unsigned short u16x4;

#define AS1 __attribute__((address_space(1)))
#define AS3 __attribute__((address_space(3)))

__device__ __forceinline__ void llds16(const void* g, void* l) {
  __builtin_amdgcn_global_load_lds((const AS1 void*)g, (AS3 void*)l, 16, 0, 0);
}

__device__ __forceinline__ unsigned short f2bf(float f) {   // RNE
  unsigned int u = __builtin_bit_cast(unsigned int, f);
  u += 0x7fffu + ((u >> 16) & 1u);
  return (unsigned short)(u >> 16);
}

__device__ __forceinline__ unsigned short f2bfru(float f) { // round-half-up
  return (unsigned short)((__builtin_bit_cast(unsigned int, f) + 0x8000u) >> 16);
}

__device__ __forceinline__ float bf2f(unsigned short u) {
  return __builtin_bit_cast(float, (unsigned int)u << 16);
}

// ---------------------------------------------------------------------------
// cast x (fp32) -> bf16, 4 elements/thread
// ---------------------------------------------------------------------------
__global__ __launch_bounds__(256) void cast_x_kernel(const float* __restrict__ in,
                                                     unsigned short* __restrict__ out) {
  int i = blockIdx.x * 256 + threadIdx.x;
  f32x4 v = ((const f32x4*)in)[i];
  u16x4 o;
  o[0] = f2bf(v[0]); o[1] = f2bf(v[1]); o[2] = f2bf(v[2]); o[3] = f2bf(v[3]);
  ((u16x4*)out)[i] = o;
}

// ---------------------------------------------------------------------------
// 4 weight transposes in one launch. W [2048][2048] fp32 -> Wt[n][k] bf16.
// ---------------------------------------------------------------------------
__global__ __launch_bounds__(256) void transpose_w4_kernel(
    const float* __restrict__ W0, const float* __restrict__ W1,
    const float* __restrict__ W2, const float* __restrict__ W3,
    unsigned short* __restrict__ T0, unsigned short* __restrict__ T1,
    unsigned short* __restrict__ T2, unsigned short* __restrict__ T3) {
  __shared__ float tile[32][33];
  const int z = blockIdx.z;
  const float* W = (z == 0) ? W0 : (z == 1) ? W1 : (z == 2) ? W2 : W3;
  unsigned short* Wt = (z == 0) ? T0 : (z == 1) ? T1 : (z == 2) ? T2 : T3;
  const int bx = blockIdx.x << 5;   // k base
  const int by = blockIdx.y << 5;   // n base
  const int tx = threadIdx.x;       // 0..31
  const int ty = threadIdx.y;       // 0..7
#pragma unroll
  for (int r = ty; r < 32; r += 8)
    tile[r][tx] = W[(size_t)(bx + r) * 2048 + by + tx];
  __syncthreads();
#pragma unroll
  for (int r = ty; r < 32; r += 8)
    Wt[(size_t)(by + r) * 2048 + bx + tx] = f2bf(tile[tx][r]);
}

// ---------------------------------------------------------------------------
// Fused QKV projection GEMM, ring-3 depth-2 prefetch.
// C[M=4096][N=6144] = X[M][K=2048] @ Wt[N][K]^T, Wt = [Wq^T|Wk^T|Wv^T].
// BM=128, BN=256, BK=64. 8 waves (2M x 4N), wave tile 64x64 (4mi x 4ni).
// LDS: 3 slots x (A 16KB + B 32KB) = 144KB. Per K-tile kt:
//   [vmcnt(6) -> s_barrier]  (tile kt's loads, issued 2 tiles ago: free wait;
//                             tile kt+1's 6 loads stay in flight)
//   stage(kt+2)              (6 global_load_lds into slot (kt+2)%3)
//   2 x { read 8 frags, 16 MFMA }   (no intra-tile sync; waves decouple)
// Rows 128B = 8 chunks of 16B, chunk swizzle c ^= row&7 both sides.
// Grid 768 flat = 3 exact CU rounds; 3 bn panels per XCD (3MB -> L2).
// Epilogue: region 0 -> Qb * 1/sqrt(T), 1 -> Kb, 2 -> Vt scatter.
// ---------------------------------------------------------------------------
__global__ __launch_bounds__(512, 2) void gemm_qkv(const unsigned short* __restrict__ A,
                                                   const unsigned short* __restrict__ Bt,
                                                   unsigned short* __restrict__ Qb,
                                                   unsigned short* __restrict__ Kb,
                                                   unsigned short* __restrict__ Vt) {
  constexpr int SLOT = 49152;                 // A 16384 + B 32768
  __shared__ __align__(16) char smem[3 * SLOT];
  const int tid  = threadIdx.x;
  const int lane = tid & 63;
  const int w    = tid >> 6;          // 0..7
  const int wr   = w >> 2;            // m-half (0..1)
  const int wc   = w & 3;             // n-quarter (0..3)
  const int q16  = lane >> 4;
  const int l15  = lane & 15;
  const int f    = blockIdx.x;
  const int g    = f >> 3;                        // 0..95
  const int bn   = (f & 7) * 3 + (g % 3);         // 0..23
  const int bm   = g / 3;                         // 0..31

  // staging sources: thread covers LDS rows srow, srow+64(,+128,+192 for B),
  // phys chunk tid&7; logical chunk = phys ^ (row&7) (row&7 == srow&7).
  const int srow = tid >> 3;                      // 0..63
  const int scl  = (tid & 7) ^ (srow & 7);
  const unsigned short* aS = A  + (size_t)((bm << 7) + srow) * 2048 + (scl << 3);
  const unsigned short* bS = Bt + (size_t)(bn * 256 + srow) * 2048 + (scl << 3);
  const int sdst = tid << 4;

  // ds_read: A row = wr*64 + mi*16 + l15, B row = wc*64 + ni*16 + l15;
  // chunk = (ks*4 + q16) ^ (row&7), row&7 == l15&7.
  const int swzb = (q16 ^ (l15 & 7)) << 4;        // ks=1: ^ 64
  const int aRd  = ((wr << 6) + l15) << 7;        // + mi*2048
  const int bRd  = 16384 + ((wc << 6) + l15) << 7 == 0 ? 0 : 16384 + (((wc << 6) + l15) << 7); // see below

  f32x4 acc[4][4];
#pragma unroll
  for (int i = 0; i < 4; ++i)
#pragma unroll
    for (int j = 0; j < 4; ++j) acc[i][j] = (f32x4){0.f, 0.f, 0.f, 0.f};

  auto stageT = [&](int kt, char* sb) {
    const size_t ko = (size_t)kt << 6;            // k element offset
    llds16(aS + ko,              sb + sdst);
    llds16(aS + (64 * 2048) + ko, sb + 8192 + sdst);
#pragma unroll
    for (int r = 0; r < 4; ++r)
      llds16(bS + (size_t)r * (64 * 2048) + ko, sb + 16384 + (r << 13) + sdst);
  };

  auto computeT = [&](const char* base) {
#pragma unroll
    for (int ks = 0; ks < 2; ++ks) {
      const int sw = swzb ^ (ks << 6);
      bf16x8 af[4], bf[4];
#pragma unroll
      for (int mi = 0; mi < 4; ++mi)
        af[mi] = *(const bf16x8*)(base + aRd + (mi << 11) + sw);
#pragma unroll
      for (int ni = 0; ni < 4; ++ni)
        bf[ni] = *(const bf16x8*)(base + 16384 + (((wc << 6) + l15) << 7) + (ni << 11) + sw);
      __builtin_amdgcn_s_setprio(1);
#pragma unroll
      for (int mi = 0; mi < 4; ++mi)
#pragma unroll
        for (int ni = 0; ni < 4; ++ni)
          acc[mi][ni] = __builtin_amdgcn_mfma_f32_16x16x32_bf16(af[mi], bf[ni], acc[mi][ni], 0, 0, 0);
      __builtin_amdgcn_s_setprio(0);
    }
  };

  char* s0 = smem;
  char* s1 = smem + SLOT;
  char* s2 = smem + 2 * SLOT;

#define W6()  asm volatile("s_waitcnt vmcnt(6)" ::: "memory")
#define W0()  asm volatile("s_waitcnt vmcnt(0)" ::: "memory")
#define BAR() __builtin_amdgcn_s_barrier()

  // prologue: tiles 0,1 staged; wait tile 0 (6 of tile 1 in flight)
  stageT(0, s0); stageT(1, s1);
  W6(); BAR();
  // kt = 0
  stageT(2, s2);
  computeT(s0);
  // kt = 1..27 (stage kt+2 <= 29)
#pragma unroll 1
  for (int b = 1; b <= 25; b += 3) {
    W6(); BAR(); stageT(b + 2, s0); computeT(s1);
    W6(); BAR(); stageT(b + 3, s1); computeT(s2);
    W6(); BAR(); stageT(b + 4, s2); computeT(s0);
  }
  // kt = 28
  W6(); BAR(); stageT(30, s0); computeT(s1);
  // kt = 29
  W6(); BAR(); stageT(31, s1); computeT(s2);
  // kt = 30
  W6(); BAR(); computeT(s0);
  // kt = 31
  W0(); BAR(); computeT(s1);

#undef W6
#undef W0
#undef BAR

  // epilogue. C/D layout: col = lane&15, row = (lane>>4)*4 + reg  [m89]
  const float qscale = 0.02209708691207961f;   // 1/sqrt(2048)
  const int rb = q16 << 2;
#pragma unroll
  for (int mi = 0; mi < 4; ++mi) {
    int m0 = (bm << 7) + (wr << 6) + (mi << 4) + rb;
#pragma unroll
    for (int ni = 0; ni < 4; ++ni) {
      int gn = (bn << 8) + (wc << 6) + (ni << 4) + l15;
      int region = gn >> 11;                     // 0 Q, 1 K, 2 V
      int nloc = gn & 2047;
      if (region == 0) {
#pragma unroll
        for (int j = 0; j < 4; ++j)
          Qb[(size_t)(m0 + j) * 2048 + nloc] = f2bf(acc[mi][ni][j] * qscale);
      } else if (region == 1) {
#pragma unroll
        for (int j = 0; j < 4; ++j)
          Kb[(size_t)(m0 + j) * 2048 + nloc] = f2bf(acc[mi][ni][j]);
      } else {
        u16x4 pk;
#pragma unroll
        for (int j = 0; j < 4; ++j) pk[j] = f2bf(acc[mi][ni][j]);
        int b = m0 >> 11, t = m0 & 2047;
        *(u16x4*)(Vt + ((size_t)((b << 4) + (nloc >> 7)) * 128 + (nloc & 127)) * 2048 + t) = pk;
      }
    }
  }
}

// ---------------------------------------------------------------------------
// Wo GEMM (round-6 structure, passing): C fp32 = A[M][K] @ Bt[N][K]^T.
// BM=128, BN=128, wave tile 64x64 (2Mx2N), 4 waves, BK=32, ring-3 LDS,
// 1 barrier + vmcnt(4)/step. Grid 512 (2 blocks/CU).
// ---------------------------------------------------------------------------
__global__ __launch_bounds__(256, 2) void gemm_wo(const unsigned short* __restrict__ A,
                                                  const unsigned short* __restrict__ Bt,
                                                  float* __restrict__ Co) {
  constexpr int SLOT = 8192 + 8192;
  __shared__ __align__(16) char smem[3 * SLOT];

  const int tid  = threadIdx.x;
  const int lane = tid & 63;
  const int w    = tid >> 6;                        // 0..3
  const int q16  = lane >> 4;
  const int l15  = lane & 15;
  const int f    = blockIdx.x;
  const int g    = f >> 3;
  const int bn   = ((f & 7) << 1) + (g & 1);
  const int bm   = g >> 1;
  const int wmb  = (w >> 1) << 6;
  const int wnb  = (w & 1) << 6;

  f32x4 acc[4][4];
#pragma unroll
  for (int i = 0; i < 4; ++i)
#pragma unroll
    for (int j = 0; j < 4; ++j) acc[i][j] = (f32x4){0.f, 0.f, 0.f, 0.f};

  const int rowA = tid >> 2;
  const int chA  = tid & 3;
  auto stageT = [&](int t, char* sb) {
    const int k0 = t << 5;
#pragma unroll
    for (int r = 0; r < 2; ++r) {
      int row = (r << 6) + rowA;
      const unsigned short* src = A + (size_t)((bm << 7) + row) * 2048 + k0
                                    + ((chA ^ ((row >> 1) & 3)) << 3);
      llds16(src, sb + (r << 12) + (w << 10));
    }
#pragma unroll
    for (int r = 0; r < 2; ++r) {
      int row = (r << 6) + rowA;
      const unsigned short* src = Bt + (size_t)((bn << 7) + row) * 2048 + k0
                                     + ((chA ^ ((row >> 1) & 3)) << 3);
      llds16(src, sb + 8192 + (r << 12) + (w << 10));
    }
  };

  auto computeT = [&](const char* base) {
    bf16x8 af[4], bf[4];
#pragma unroll
    for (int mi = 0; mi < 4; ++mi) {
      int row = wmb + (mi << 4) + l15;
      af[mi] = *(const bf16x8*)(base + (row << 6) + ((q16 ^ ((row >> 1) & 3)) << 4));
    }
#pragma unroll
    for (int ni = 0; ni < 4; ++ni) {
      int row = wnb + (ni << 4) + l15;
      bf[ni] = *(const bf16x8*)(base + 8192 + (row << 6) + ((q16 ^ ((row >> 1) & 3)) << 4));
    }
    __builtin_amdgcn_s_setprio(1);
#pragma unroll
    for (int mi = 0; mi < 4; ++mi)
#pragma unroll
      for (int ni = 0; ni < 4; ++ni)
        acc[mi][ni] = __builtin_amdgcn_mfma_f32_16x16x32_bf16(af[mi], bf[ni], acc[mi][ni], 0, 0, 0);
    __builtin_amdgcn_s_setprio(0);
  };

  auto STEP = [&](int t, char* cbase, char* sbase) {
    asm volatile("s_waitcnt vmcnt(4)" ::: "memory");
    __builtin_amdgcn_s_barrier();
    stageT(t + 2, sbase);
    computeT(cbase);
  };

  char* s0 = smem;
  char* s1 = smem + SLOT;
  char* s2 = smem + 2 * SLOT;

  stageT(0, s0); stageT(1, s1);
#pragma unroll 1
  for (int t = 0; t < 60; t += 3) {
    STEP(t,     s0, s2);
    STEP(t + 1, s1, s0);
    STEP(t + 2, s2, s1);
  }
  STEP(60, s0, s2);
  STEP(61, s1, s0);
  asm volatile("s_waitcnt vmcnt(4)" ::: "memory");
  __builtin_amdgcn_s_barrier();
  computeT(s2);
  asm volatile("s_waitcnt vmcnt(0)" ::: "memory");
  __builtin_amdgcn_s_barrier();
  computeT(s0);

  const int rb = q16 << 2;
#pragma unroll
  for (int mi = 0; mi < 4; ++mi) {
    int m0 = (bm << 7) + wmb + (mi << 4) + rb;
#pragma unroll
    for (int ni = 0; ni < 4; ++ni) {
      int n = (bn << 7) + wnb + (ni << 4) + l15;
#pragma unroll
      for (int j = 0; j < 4; ++j)
        Co[(size_t)(m0 + j) * 2048 + n] = acc[mi][ni][j];
    }
  }
}

// ---------------------------------------------------------------------------
// V suffix sums at 32-row granularity.
// Suf[j][bh][d] = sum_{s >= 32j} V[b, s, h, d],  j in 0..64 (Suf[64] = 0).
// ---------------------------------------------------------------------------
__global__ __launch_bounds__(256) void vsuf_kernel(const unsigned short* __restrict__ Vt,
                                                   float* __restrict__ Suf) {
  const int row  = blockIdx.x * 4 + (threadIdx.x >> 6);  // 0..4095
  const int lane = threadIdx.x & 63;
  const unsigned short* vp = Vt + (size_t)row * 2048 + (lane << 5);
  float a = 0.f;
#pragma unroll
  for (int c = 0; c < 4; ++c) {
    bf16x8 v = *(const bf16x8*)(vp + (c << 3));
#pragma unroll
    for (int j = 0; j < 8; ++j) a += bf2f((unsigned short)v[j]);
  }
  float I = a;
#pragma unroll
  for (int off = 1; off < 64; off <<= 1) {
    float t = __shfl_down(I, off, 64);
    I += (lane + off < 64) ? t : 0.f;
  }
  Suf[(size_t)lane * 4096 + row] = I;
  if (lane == 0) Suf[(size_t)64 * 4096 + row] = 0.f;
}

// ---------------------------------------------------------------------------
// Fused attention, causal-skipped. Flat grid 1024; decode:
//   xcd = f&7, bh = xcd*4 + ((f>>3)&3), strip = 31 - (f>>5)  (LPT order)
// Q is PRE-SCALED by 1/sqrt(T). Mask only on the straddling tile. Tiles
// above the diagonal covered by V-suffix sums (p == 1 exactly there).
// ---------------------------------------------------------------------------
__global__ __launch_bounds__(256) void attn_kernel(const unsigned short* __restrict__ Q,
                                                   const unsigned short* __restrict__ K,
                                                   const unsigned short* __restrict__ V,  // Vt layout
                                                   const float* __restrict__ Suf,
                                                   unsigned short* __restrict__ O) {
  __shared__ __align__(16) char smem[36864];  // K dbuf 2x8K | V dbuf 2x8K | P 4x1K
  const int tid  = threadIdx.x;
  const int lane = tid & 63;
  const int w    = tid >> 6;
  const int q16  = lane >> 4;
  const int l15  = lane & 15;
  const int f    = blockIdx.x;
  const int bh    = ((f & 7) << 2) + ((f >> 3) & 3);
  const int strip = 31 - (f >> 5);
  const int b  = bh >> 4;
  const size_t qkbase = ((size_t)(b << 11)) * 2048 + ((size_t)(bh & 15) << 7);
  const size_t vbase  = (size_t)bh << 18;     // bh*128*2048
  const int rb = q16 << 2;
  char* Psm = smem + 32768 + (w << 10);

  const int numIter = 2 * strip + 2;
  const int t0 = (strip << 6) + (w << 4);

  auto stage = [&](int s0, int kb, int vb) {
#pragma unroll
    for (int c = 0; c < 2; ++c) {
      int ch = (w << 1) + c;
      int rowK = (ch << 2) + q16;                        // 4 rows / 1KB chunk
      int colbK = (l15 << 4) ^ ((rowK & 7) << 4);
      llds16(K + qkbase + (size_t)(s0 + rowK) * 2048 + (colbK >> 1), smem + kb + (ch << 10));
      int rowV = (ch << 4) + (lane >> 2);                // 16 rows / 1KB chunk
      int colbV = ((lane & 3) << 4) ^ (((rowV >> 2) & 3) << 4);
      llds16(V + vbase + (size_t)rowV * 2048 + s0 + (colbV >> 1), smem + vb + (ch << 10));
    }
  };

  // Q fragments: lane holds Q[t0 + (lane&15)][8*(lane>>4) + j + 32*kk]
  bf16x8 qf[4];
  {
    const unsigned short* qp = Q + qkbase + (size_t)(t0 + l15) * 2048 + (q16 << 3);
#pragma unroll
    for (int kk = 0; kk < 4; ++kk) qf[kk] = *(const bf16x8*)(qp + (kk << 5));
  }

  f32x4 oacc[8];
#pragma unroll
  for (int i = 0; i < 8; ++i) oacc[i] = (f32x4){0.f, 0.f, 0.f, 0.f};
  float ell[4] = {0.f, 0.f, 0.f, 0.f};   // per-lane partial; reduced in epilogue

  stage(0, 0, 16384);
  asm volatile("s_waitcnt vmcnt(0)" ::: "memory");
  __syncthreads();

  int cur = 0;
  for (int it = 0; it < numIter; ++it) {
    const int s0 = it << 5;
    if (it + 1 < numIter)
      stage(s0 + 32, (cur ^ 1) << 13, 16384 + ((cur ^ 1) << 13));

    if (s0 <= t0) {   // tile not entirely above this wave's diagonal
      const int kb = cur << 13;
      const int vb = 16384 + (cur << 13);

      // QK^T: two 16-col s-tiles (scores already scaled via Q)
      f32x4 sA = (f32x4){0.f, 0.f, 0.f, 0.f}, sB = (f32x4){0.f, 0.f, 0.f, 0.f};
#pragma unroll
      for (int kk = 0; kk < 4; ++kk) {
        int r0 = l15;
        bf16x8 k0f = *(const bf16x8*)(smem + kb + (r0 << 8) + (((kk << 6) + (q16 << 4)) ^ ((r0 & 7) << 4)));
        sA = __builtin_amdgcn_mfma_f32_16x16x32_bf16(qf[kk], k0f, sA, 0, 0, 0);
        int r1 = 16 + l15;
        bf16x8 k1f = *(const bf16x8*)(smem + kb + (r1 << 8) + (((kk << 6) + (q16 << 4)) ^ ((r1 & 7) << 4)));
        sB = __builtin_amdgcn_mfma_f32_16x16x32_bf16(qf[kk], k1f, sB, 0, 0, 0);
      }

      float pA[4], pB[4];
      if (s0 + 31 <= t0) {           // fully unmasked tile (the common case)
#pragma unroll
        for (int j = 0; j < 4; ++j) {
          pA[j] = __expf(sA[j]);
          pB[j] = __expf(sB[j]);
          ell[j] += pA[j] + pB[j];
        }
      } else {                       // straddling tile: mask -> exp(0)=1
#pragma unroll
        for (int j = 0; j < 4; ++j) {
          int t  = t0 + rb + j;
          int sa = s0 + l15;
          float vA = (sa <= t)      ? sA[j] : 0.f;
          float vB = (sa + 16 <= t) ? sB[j] : 0.f;
          pA[j] = __expf(vA);
          pB[j] = __expf(vB);
          ell[j] += pA[j] + pB[j];
        }
      }

      // P -> per-wave LDS [16 t][32 s] bf16, swz: col ^= ((row>>1)&3)<<4
#pragma unroll
      for (int j = 0; j < 4; ++j) {
        int r   = rb + j;
        int swz = ((r >> 1) & 3) << 4;
        *(unsigned short*)(Psm + (r << 6) + ((l15 << 1) ^ swz))        = f2bfru(pA[j]);
        *(unsigned short*)(Psm + (r << 6) + ((32 + (l15 << 1)) ^ swz)) = f2bfru(pB[j]);
      }
      asm volatile("s_waitcnt lgkmcnt(0)" ::: "memory");

      bf16x8 pa;
      {
        int r = l15;
        pa = *(const bf16x8*)(Psm + (r << 6) + ((q16 << 4) ^ (((r >> 1) & 3) << 4)));
      }
#pragma unroll
      for (int ni = 0; ni < 8; ++ni) {
        int dr = (ni << 4) + l15;
        bf16x8 vbf = *(const bf16x8*)(smem + vb + (dr << 6) + ((q16 << 4) ^ (((dr >> 2) & 3) << 4)));
        oacc[ni] = __builtin_amdgcn_mfma_f32_16x16x32_bf16(pa, vbf, oacc[ni], 0, 0, 0);
      }
    }

    asm volatile("s_waitcnt vmcnt(0)" ::: "memory");
    __syncthreads();
    cur ^= 1;
  }

  // suffix correction: all s >= send have p == 1 exactly.
  const int send = (t0 & ~31) + 32;
  const float* sp = Suf + (size_t)(send >> 5) * 4096 + ((size_t)bh << 7);
  const float extra = (float)(2048 - send);
#pragma unroll
  for (int ni = 0; ni < 8; ++ni) {
    float sv = sp[(ni << 4) + l15];
#pragma unroll
    for (int j = 0; j < 4; ++j) oacc[ni][j] += sv;
  }

  // deferred ell reduction (within each 16-lane row group), then normalize
#pragma unroll
  for (int j = 0; j < 4; ++j) {
    float r = ell[j];
    r += __shfl_xor(r, 1, 64);
    r += __shfl_xor(r, 2, 64);
    r += __shfl_xor(r, 4, 64);
    r += __shfl_xor(r, 8, 64);
    float inv = 1.0f / (r + extra);
    int t = t0 + rb + j;
    unsigned short* op = O + qkbase + (size_t)t * 2048;
#pragma unroll
    for (int ni = 0; ni < 8; ++ni)
      op[(ni << 4) + l15] = f2bf(oacc[ni][j] * inv);
  }
}

// ---------------------------------------------------------------------------
// launch
// ---------------------------------------------------------------------------
extern "C" void kernel_launch(void* const* d_in, const int* in_sizes, int n_in,
                              void* d_out, int out_size, void* d_ws, size_t ws_size,
                              hipStream_t stream) {
  (void)in_sizes; (void)n_in; (void)out_size; (void)ws_size;
  const float* x  = (const float*)d_in[0];
  const float* Wq = (const float*)d_in[1];
  const float* Wk = (const float*)d_in[2];
  const float* Wv = (const float*)d_in[3];
  const float* Wo = (const float*)d_in[4];
  float* out = (float*)d_out;

  char* ws = (char*)d_ws;
  unsigned short* Xb  = (unsigned short*)(ws);                        // 16 MiB (reused as O)
  unsigned short* Wqt = (unsigned short*)(ws + 16777216);             // 8 MiB (reused as Suf)
  unsigned short* Wkt = (unsigned short*)(ws + 16777216 + 8388608);
  unsigned short* Wvt = (unsigned short*)(ws + 16777216 + 2 * 8388608);
  unsigned short* Wot = (unsigned short*)(ws + 16777216 + 3 * 8388608);
  unsigned short* Qb  = (unsigned short*)(ws + 50331648);             // 16 MiB
  unsigned short* Kb  = (unsigned short*)(ws + 67108864);             // 16 MiB
  unsigned short* Vt  = (unsigned short*)(ws + 83886080);             // 16 MiB
  unsigned short* Ob  = Xb;          // X dead after the QKV projection
  float*          Suf = (float*)Wqt; // W^T dead after the QKV projection

  cast_x_kernel<<<8192, 256, 0, stream>>>(x, Xb);
  {
    dim3 tb(32, 8), tg(64, 64, 4);
    transpose_w4_kernel<<<tg, tb, 0, stream>>>(Wq, Wk, Wv, Wo, Wqt, Wkt, Wvt, Wot);
  }
  // fused QKV projection: Bt = [Wqt|Wkt|Wvt] (contiguous), N=6144
  gemm_qkv<<<768, 512, 0, stream>>>(Xb, Wqt, Qb, Kb, Vt);

  vsuf_kernel<<<1024, 256, 0, stream>>>(Vt, Suf);

  attn_kernel<<<1024, 256, 0, stream>>>(Qb, Kb, Vt, Suf, Ob);

  gemm_wo<<<512, 256, 0, stream>>>(Ob, Wot, out);
}

// Round 9
// 262.053 us; speedup vs baseline: 1.0139x; 1.0139x over previous
//
#include <hip/hip_runtime.h>

// ---------------------------------------------------------------------------
// MultiHeadAttention forward, MI355X/gfx950.
// B=2, T=2048, D=2048, H=16, Dh=128. fp32 in/out, bf16 MFMA internally.
// Reference quirks (faithful): multiplicative tril mask (masked scores = 0,
// NOT -inf -> exp(0)=1 contributions over ALL 2048 cols), scale = 1/sqrt(T).
// Round 9: QKV GEMM -> wave tile 64x96 (FLOP/LDS-byte 38.4 vs 32: -39%
// LDS reads, the measured bottleneck), BM=128 BN=384 BK=32, 8 waves,
// ring-3 32KB slots (96KB), depth-2 counted vmcnt(4), 1 barrier/K-tile,
// grid 512 = 2 exact CU rounds. Wo + attn unchanged (passing).
// ---------------------------------------------------------------------------

typedef __attribute__((ext_vector_type(4))) float  f32x4;
typedef __attribute__((ext_vector_type(8))) short  bf16x8;
typedef __attribute__((ext_vector_type(4))) unsigned short u16x4;

#define AS1 __attribute__((address_space(1)))
#define AS3 __attribute__((address_space(3)))

__device__ __forceinline__ void llds16(const void* g, void* l) {
  __builtin_amdgcn_global_load_lds((const AS1 void*)g, (AS3 void*)l, 16, 0, 0);
}

__device__ __forceinline__ unsigned short f2bf(float f) {   // RNE
  unsigned int u = __builtin_bit_cast(unsigned int, f);
  u += 0x7fffu + ((u >> 16) & 1u);
  return (unsigned short)(u >> 16);
}

__device__ __forceinline__ unsigned short f2bfru(float f) { // round-half-up
  return (unsigned short)((__builtin_bit_cast(unsigned int, f) + 0x8000u) >> 16);
}

__device__ __forceinline__ float bf2f(unsigned short u) {
  return __builtin_bit_cast(float, (unsigned int)u << 16);
}

// ---------------------------------------------------------------------------
// cast x (fp32) -> bf16, 4 elements/thread
// ---------------------------------------------------------------------------
__global__ __launch_bounds__(256) void cast_x_kernel(const float* __restrict__ in,
                                                     unsigned short* __restrict__ out) {
  int i = blockIdx.x * 256 + threadIdx.x;
  f32x4 v = ((const f32x4*)in)[i];
  u16x4 o;
  o[0] = f2bf(v[0]); o[1] = f2bf(v[1]); o[2] = f2bf(v[2]); o[3] = f2bf(v[3]);
  ((u16x4*)out)[i] = o;
}

// ---------------------------------------------------------------------------
// 4 weight transposes in one launch. W [2048][2048] fp32 -> Wt[n][k] bf16.
// ---------------------------------------------------------------------------
__global__ __launch_bounds__(256) void transpose_w4_kernel(
    const float* __restrict__ W0, const float* __restrict__ W1,
    const float* __restrict__ W2, const float* __restrict__ W3,
    unsigned short* __restrict__ T0, unsigned short* __restrict__ T1,
    unsigned short* __restrict__ T2, unsigned short* __restrict__ T3) {
  __shared__ float tile[32][33];
  const int z = blockIdx.z;
  const float* W = (z == 0) ? W0 : (z == 1) ? W1 : (z == 2) ? W2 : W3;
  unsigned short* Wt = (z == 0) ? T0 : (z == 1) ? T1 : (z == 2) ? T2 : T3;
  const int bx = blockIdx.x << 5;   // k base
  const int by = blockIdx.y << 5;   // n base
  const int tx = threadIdx.x;       // 0..31
  const int ty = threadIdx.y;       // 0..7
#pragma unroll
  for (int r = ty; r < 32; r += 8)
    tile[r][tx] = W[(size_t)(bx + r) * 2048 + by + tx];
  __syncthreads();
#pragma unroll
  for (int r = ty; r < 32; r += 8)
    Wt[(size_t)(by + r) * 2048 + bx + tx] = f2bf(tile[tx][r]);
}

// ---------------------------------------------------------------------------
// Fused QKV projection GEMM, ring-3 depth-2, wave tile 64x96.
// C[M=4096][N=6144] = X[M][K=2048] @ Wt[N][K]^T, Wt = [Wq^T|Wk^T|Wv^T].
// BM=128, BN=384, BK=32. 8 waves (2M x 4N), wave tile 64x96 (4mi x 6ni),
// acc 96 VGPR. LDS: 3 slots x (A 8KB + B 24KB) = 96KB -> 1 block/CU.
// Per K-tile kt: [vmcnt(4) -> s_barrier] (tile kt's 4 loads issued 2 tiles
// ago: free; tile kt+1's 4 stay in flight) ; stage(kt+2) (4 gloads) ;
// { read 4 A + 6 B frags, 24 MFMA } free-running (no intra-tile sync).
// Rows 64B = 4 chunks of 16B, chunk c ^= (row>>1)&3 both sides (2-way max).
// Grid 512 flat = 2 exact CU rounds; 2 bn panels per XCD (3MB -> L2).
// Epilogue per element: region 0 -> Qb * 1/sqrt(T), 1 -> Kb, 2 -> Vt.
// ---------------------------------------------------------------------------
__global__ __launch_bounds__(512, 2) void gemm_qkv2(const unsigned short* __restrict__ A,
                                                    const unsigned short* __restrict__ Bt,
                                                    unsigned short* __restrict__ Qb,
                                                    unsigned short* __restrict__ Kb,
                                                    unsigned short* __restrict__ Vt) {
  constexpr int SLOT = 32768;                 // A 8192 + B 24576
  __shared__ __align__(16) char smem[3 * SLOT];
  const int tid  = threadIdx.x;
  const int lane = tid & 63;
  const int w    = tid >> 6;          // 0..7
  const int wr   = w >> 2;            // m-half (0..1)
  const int wc   = w & 3;             // n-quarter (0..3)
  const int q16  = lane >> 4;
  const int l15  = lane & 15;
  const int f    = blockIdx.x;
  const int bn   = ((f & 7) << 1) + ((f >> 3) & 1);   // 0..15
  const int bm   = f >> 4;                            // 0..31

  // staging: combined [A(128) ; B(384)] rows of 64B; 4 rounds of 128 rows.
  // thread t -> row t>>2 (in-round), phys chunk t&3, logical = phys ^ swz(row);
  // round bases are multiples of 128 rows so swz(row) == swz(srow).
  const int srow = tid >> 2;                          // 0..127
  const int scl  = (tid & 3) ^ ((srow >> 1) & 3);
  const unsigned short* aS = A  + (size_t)((bm << 7) + srow) * 2048 + (scl << 3);
  const unsigned short* bS = Bt + (size_t)(bn * 384 + srow) * 2048 + (scl << 3);
  const int sdst = tid << 4;

  // ds_read: row = 16-aligned base + l15 -> swz = (l15>>1)&3 lane-constant.
  const int swx   = (q16 ^ ((l15 >> 1) & 3)) << 4;
  const int aBase = (((wr << 6) + l15) << 6) + swx;            // + mi*1024
  const int bBase = 8192 + ((wc * 96 + l15) << 6) + swx;       // + ni*1024

  f32x4 acc[4][6];
#pragma unroll
  for (int i = 0; i < 4; ++i)
#pragma unroll
    for (int j = 0; j < 6; ++j) acc[i][j] = (f32x4){0.f, 0.f, 0.f, 0.f};

  auto stageT = [&](int kt, char* sb) {
    const size_t ko = (size_t)kt << 5;                // k element offset
    llds16(aS + ko, sb + sdst);
#pragma unroll
    for (int r = 0; r < 3; ++r)
      llds16(bS + (size_t)r * (128 * 2048) + ko, sb + 8192 + (r << 13) + sdst);
  };

  auto computeT = [&](const char* base) {
    bf16x8 af[4], bf[6];
#pragma unroll
    for (int mi = 0; mi < 4; ++mi)
      af[mi] = *(const bf16x8*)(base + aBase + (mi << 10));
#pragma unroll
    for (int ni = 0; ni < 6; ++ni)
      bf[ni] = *(const bf16x8*)(base + bBase + (ni << 10));
    __builtin_amdgcn_s_setprio(1);
#pragma unroll
    for (int mi = 0; mi < 4; ++mi)
#pragma unroll
      for (int ni = 0; ni < 6; ++ni)
        acc[mi][ni] = __builtin_amdgcn_mfma_f32_16x16x32_bf16(af[mi], bf[ni], acc[mi][ni], 0, 0, 0);
    __builtin_amdgcn_s_setprio(0);
  };

  char* s0 = smem;
  char* s1 = smem + SLOT;
  char* s2 = smem + 2 * SLOT;

#define W4()  asm volatile("s_waitcnt vmcnt(4)" ::: "memory")
#define WZ()  asm volatile("s_waitcnt vmcnt(0)" ::: "memory")
#define BAR() __builtin_amdgcn_s_barrier()

  // prologue: tiles 0,1 staged (8 loads); wait tile 0 (tile 1 in flight)
  stageT(0, s0); stageT(1, s1);
  W4(); BAR();
  stageT(2, s2); computeT(s0);                  // kt = 0
  // kt = 1..60 (stages up to 62), slots rotate mod 3
#pragma unroll 1
  for (int kt = 1; kt <= 58; kt += 3) {
    W4(); BAR(); stageT(kt + 2, s0); computeT(s1);
    W4(); BAR(); stageT(kt + 3, s1); computeT(s2);
    W4(); BAR(); stageT(kt + 4, s2); computeT(s0);
  }
  // kt = 61
  W4(); BAR(); stageT(63, s0); computeT(s1);
  // kt = 62
  W4(); BAR(); computeT(s2);
  // kt = 63
  WZ(); BAR(); computeT(s0);

#undef W4
#undef WZ
#undef BAR

  // epilogue. C/D layout: col = lane&15, row = (lane>>4)*4 + reg  [m89]
  const float qscale = 0.02209708691207961f;   // 1/sqrt(2048)
  const int rb = q16 << 2;
#pragma unroll
  for (int mi = 0; mi < 4; ++mi) {
    int m0 = (bm << 7) + (wr << 6) + (mi << 4) + rb;
#pragma unroll
    for (int ni = 0; ni < 6; ++ni) {
      int gn = bn * 384 + wc * 96 + (ni << 4) + l15;
      int region = gn >> 11;                     // 0 Q, 1 K, 2 V
      int nloc = gn & 2047;
      if (region == 0) {
#pragma unroll
        for (int j = 0; j < 4; ++j)
          Qb[(size_t)(m0 + j) * 2048 + nloc] = f2bf(acc[mi][ni][j] * qscale);
      } else if (region == 1) {
#pragma unroll
        for (int j = 0; j < 4; ++j)
          Kb[(size_t)(m0 + j) * 2048 + nloc] = f2bf(acc[mi][ni][j]);
      } else {
        u16x4 pk;
#pragma unroll
        for (int j = 0; j < 4; ++j) pk[j] = f2bf(acc[mi][ni][j]);
        int b = m0 >> 11, t = m0 & 2047;
        *(u16x4*)(Vt + ((size_t)((b << 4) + (nloc >> 7)) * 128 + (nloc & 127)) * 2048 + t) = pk;
      }
    }
  }
}

// ---------------------------------------------------------------------------
// Wo GEMM (round-6 structure, passing): C fp32 = A[M][K] @ Bt[N][K]^T.
// BM=128, BN=128, wave tile 64x64 (2Mx2N), 4 waves, BK=32, ring-3 LDS,
// 1 barrier + vmcnt(4)/step. Grid 512 (2 blocks/CU).
// ---------------------------------------------------------------------------
__global__ __launch_bounds__(256, 2) void gemm_wo(const unsigned short* __restrict__ A,
                                                  const unsigned short* __restrict__ Bt,
                                                  float* __restrict__ Co) {
  constexpr int SLOT = 8192 + 8192;
  __shared__ __align__(16) char smem[3 * SLOT];

  const int tid  = threadIdx.x;
  const int lane = tid & 63;
  const int w    = tid >> 6;                        // 0..3
  const int q16  = lane >> 4;
  const int l15  = lane & 15;
  const int f    = blockIdx.x;
  const int g    = f >> 3;
  const int bn   = ((f & 7) << 1) + (g & 1);
  const int bm   = g >> 1;
  const int wmb  = (w >> 1) << 6;
  const int wnb  = (w & 1) << 6;

  f32x4 acc[4][4];
#pragma unroll
  for (int i = 0; i < 4; ++i)
#pragma unroll
    for (int j = 0; j < 4; ++j) acc[i][j] = (f32x4){0.f, 0.f, 0.f, 0.f};

  const int rowA = tid >> 2;
  const int chA  = tid & 3;
  auto stageT = [&](int t, char* sb) {
    const int k0 = t << 5;
#pragma unroll
    for (int r = 0; r < 2; ++r) {
      int row = (r << 6) + rowA;
      const unsigned short* src = A + (size_t)((bm << 7) + row) * 2048 + k0
                                    + ((chA ^ ((row >> 1) & 3)) << 3);
      llds16(src, sb + (r << 12) + (w << 10));
    }
#pragma unroll
    for (int r = 0; r < 2; ++r) {
      int row = (r << 6) + rowA;
      const unsigned short* src = Bt + (size_t)((bn << 7) + row) * 2048 + k0
                                     + ((chA ^ ((row >> 1) & 3)) << 3);
      llds16(src, sb + 8192 + (r << 12) + (w << 10));
    }
  };

  auto computeT = [&](const char* base) {
    bf16x8 af[4], bf[4];
#pragma unroll
    for (int mi = 0; mi < 4; ++mi) {
      int row = wmb + (mi << 4) + l15;
      af[mi] = *(const bf16x8*)(base + (row << 6) + ((q16 ^ ((row >> 1) & 3)) << 4));
    }
#pragma unroll
    for (int ni = 0; ni < 4; ++ni) {
      int row = wnb + (ni << 4) + l15;
      bf[ni] = *(const bf16x8*)(base + 8192 + (row << 6) + ((q16 ^ ((row >> 1) & 3)) << 4));
    }
    __builtin_amdgcn_s_setprio(1);
#pragma unroll
    for (int mi = 0; mi < 4; ++mi)
#pragma unroll
      for (int ni = 0; ni < 4; ++ni)
        acc[mi][ni] = __builtin_amdgcn_mfma_f32_16x16x32_bf16(af[mi], bf[ni], acc[mi][ni], 0, 0, 0);
    __builtin_amdgcn_s_setprio(0);
  };

  auto STEP = [&](int t, char* cbase, char* sbase) {
    asm volatile("s_waitcnt vmcnt(4)" ::: "memory");
    __builtin_amdgcn_s_barrier();
    stageT(t + 2, sbase);
    computeT(cbase);
  };

  char* s0 = smem;
  char* s1 = smem + SLOT;
  char* s2 = smem + 2 * SLOT;

  stageT(0, s0); stageT(1, s1);
#pragma unroll 1
  for (int t = 0; t < 60; t += 3) {
    STEP(t,     s0, s2);
    STEP(t + 1, s1, s0);
    STEP(t + 2, s2, s1);
  }
  STEP(60, s0, s2);
  STEP(61, s1, s0);
  asm volatile("s_waitcnt vmcnt(4)" ::: "memory");
  __builtin_amdgcn_s_barrier();
  computeT(s2);
  asm volatile("s_waitcnt vmcnt(0)" ::: "memory");
  __builtin_amdgcn_s_barrier();
  computeT(s0);

  const int rb = q16 << 2;
#pragma unroll
  for (int mi = 0; mi < 4; ++mi) {
    int m0 = (bm << 7) + wmb + (mi << 4) + rb;
#pragma unroll
    for (int ni = 0; ni < 4; ++ni) {
      int n = (bn << 7) + wnb + (ni << 4) + l15;
#pragma unroll
      for (int j = 0; j < 4; ++j)
        Co[(size_t)(m0 + j) * 2048 + n] = acc[mi][ni][j];
    }
  }
}

// ---------------------------------------------------------------------------
// V suffix sums at 32-row granularity.
// Suf[j][bh][d] = sum_{s >= 32j} V[b, s, h, d],  j in 0..64 (Suf[64] = 0).
// ---------------------------------------------------------------------------
__global__ __launch_bounds__(256) void vsuf_kernel(const unsigned short* __restrict__ Vt,
                                                   float* __restrict__ Suf) {
  const int row  = blockIdx.x * 4 + (threadIdx.x >> 6);  // 0..4095
  const int lane = threadIdx.x & 63;
  const unsigned short* vp = Vt + (size_t)row * 2048 + (lane << 5);
  float a = 0.f;
#pragma unroll
  for (int c = 0; c < 4; ++c) {
    bf16x8 v = *(const bf16x8*)(vp + (c << 3));
#pragma unroll
    for (int j = 0; j < 8; ++j) a += bf2f((unsigned short)v[j]);
  }
  float I = a;
#pragma unroll
  for (int off = 1; off < 64; off <<= 1) {
    float t = __shfl_down(I, off, 64);
    I += (lane + off < 64) ? t : 0.f;
  }
  Suf[(size_t)lane * 4096 + row] = I;
  if (lane == 0) Suf[(size_t)64 * 4096 + row] = 0.f;
}

// ---------------------------------------------------------------------------
// Fused attention, causal-skipped. Flat grid 1024; decode:
//   xcd = f&7, bh = xcd*4 + ((f>>3)&3), strip = 31 - (f>>5)  (LPT order)
// Q is PRE-SCALED by 1/sqrt(T). Mask only on the straddling tile. Tiles
// above the diagonal covered by V-suffix sums (p == 1 exactly there).
// ---------------------------------------------------------------------------
__global__ __launch_bounds__(256) void attn_kernel(const unsigned short* __restrict__ Q,
                                                   const unsigned short* __restrict__ K,
                                                   const unsigned short* __restrict__ V,  // Vt layout
                                                   const float* __restrict__ Suf,
                                                   unsigned short* __restrict__ O) {
  __shared__ __align__(16) char smem[36864];  // K dbuf 2x8K | V dbuf 2x8K | P 4x1K
  const int tid  = threadIdx.x;
  const int lane = tid & 63;
  const int w    = tid >> 6;
  const int q16  = lane >> 4;
  const int l15  = lane & 15;
  const int f    = blockIdx.x;
  const int bh    = ((f & 7) << 2) + ((f >> 3) & 3);
  const int strip = 31 - (f >> 5);
  const int b  = bh >> 4;
  const size_t qkbase = ((size_t)(b << 11)) * 2048 + ((size_t)(bh & 15) << 7);
  const size_t vbase  = (size_t)bh << 18;     // bh*128*2048
  const int rb = q16 << 2;
  char* Psm = smem + 32768 + (w << 10);

  const int numIter = 2 * strip + 2;
  const int t0 = (strip << 6) + (w << 4);

  auto stage = [&](int s0, int kb, int vb) {
#pragma unroll
    for (int c = 0; c < 2; ++c) {
      int ch = (w << 1) + c;
      int rowK = (ch << 2) + q16;                        // 4 rows / 1KB chunk
      int colbK = (l15 << 4) ^ ((rowK & 7) << 4);
      llds16(K + qkbase + (size_t)(s0 + rowK) * 2048 + (colbK >> 1), smem + kb + (ch << 10));
      int rowV = (ch << 4) + (lane >> 2);                // 16 rows / 1KB chunk
      int colbV = ((lane & 3) << 4) ^ (((rowV >> 2) & 3) << 4);
      llds16(V + vbase + (size_t)rowV * 2048 + s0 + (colbV >> 1), smem + vb + (ch << 10));
    }
  };

  // Q fragments: lane holds Q[t0 + (lane&15)][8*(lane>>4) + j + 32*kk]
  bf16x8 qf[4];
  {
    const unsigned short* qp = Q + qkbase + (size_t)(t0 + l15) * 2048 + (q16 << 3);
#pragma unroll
    for (int kk = 0; kk < 4; ++kk) qf[kk] = *(const bf16x8*)(qp + (kk << 5));
  }

  f32x4 oacc[8];
#pragma unroll
  for (int i = 0; i < 8; ++i) oacc[i] = (f32x4){0.f, 0.f, 0.f, 0.f};
  float ell[4] = {0.f, 0.f, 0.f, 0.f};   // per-lane partial; reduced in epilogue

  stage(0, 0, 16384);
  asm volatile("s_waitcnt vmcnt(0)" ::: "memory");
  __syncthreads();

  int cur = 0;
  for (int it = 0; it < numIter; ++it) {
    const int s0 = it << 5;
    if (it + 1 < numIter)
      stage(s0 + 32, (cur ^ 1) << 13, 16384 + ((cur ^ 1) << 13));

    if (s0 <= t0) {   // tile not entirely above this wave's diagonal
      const int kb = cur << 13;
      const int vb = 16384 + (cur << 13);

      // QK^T: two 16-col s-tiles (scores already scaled via Q)
      f32x4 sA = (f32x4){0.f, 0.f, 0.f, 0.f}, sB = (f32x4){0.f, 0.f, 0.f, 0.f};
#pragma unroll
      for (int kk = 0; kk < 4; ++kk) {
        int r0 = l15;
        bf16x8 k0f = *(const bf16x8*)(smem + kb + (r0 << 8) + (((kk << 6) + (q16 << 4)) ^ ((r0 & 7) << 4)));
        sA = __builtin_amdgcn_mfma_f32_16x16x32_bf16(qf[kk], k0f, sA, 0, 0, 0);
        int r1 = 16 + l15;
        bf16x8 k1f = *(const bf16x8*)(smem + kb + (r1 << 8) + (((kk << 6) + (q16 << 4)) ^ ((r1 & 7) << 4)));
        sB = __builtin_amdgcn_mfma_f32_16x16x32_bf16(qf[kk], k1f, sB, 0, 0, 0);
      }

      float pA[4], pB[4];
      if (s0 + 31 <= t0) {           // fully unmasked tile (the common case)
#pragma unroll
        for (int j = 0; j < 4; ++j) {
          pA[j] = __expf(sA[j]);
          pB[j] = __expf(sB[j]);
          ell[j] += pA[j] + pB[j];
        }
      } else {                       // straddling tile: mask -> exp(0)=1
#pragma unroll
        for (int j = 0; j < 4; ++j) {
          int t  = t0 + rb + j;
          int sa = s0 + l15;
          float vA = (sa <= t)      ? sA[j] : 0.f;
          float vB = (sa + 16 <= t) ? sB[j] : 0.f;
          pA[j] = __expf(vA);
          pB[j] = __expf(vB);
          ell[j] += pA[j] + pB[j];
        }
      }

      // P -> per-wave LDS [16 t][32 s] bf16, swz: col ^= ((row>>1)&3)<<4
#pragma unroll
      for (int j = 0; j < 4; ++j) {
        int r   = rb + j;
        int swz = ((r >> 1) & 3) << 4;
        *(unsigned short*)(Psm + (r << 6) + ((l15 << 1) ^ swz))        = f2bfru(pA[j]);
        *(unsigned short*)(Psm + (r << 6) + ((32 + (l15 << 1)) ^ swz)) = f2bfru(pB[j]);
      }
      asm volatile("s_waitcnt lgkmcnt(0)" ::: "memory");

      bf16x8 pa;
      {
        int r = l15;
        pa = *(const bf16x8*)(Psm + (r << 6) + ((q16 << 4) ^ (((r >> 1) & 3) << 4)));
      }
#pragma unroll
      for (int ni = 0; ni < 8; ++ni) {
        int dr = (ni << 4) + l15;
        bf16x8 vbf = *(const bf16x8*)(smem + vb + (dr << 6) + ((q16 << 4) ^ (((dr >> 2) & 3) << 4)));
        oacc[ni] = __builtin_amdgcn_mfma_f32_16x16x32_bf16(pa, vbf, oacc[ni], 0, 0, 0);
      }
    }

    asm volatile("s_waitcnt vmcnt(0)" ::: "memory");
    __syncthreads();
    cur ^= 1;
  }

  // suffix correction: all s >= send have p == 1 exactly.
  const int send = (t0 & ~31) + 32;
  const float* sp = Suf + (size_t)(send >> 5) * 4096 + ((size_t)bh << 7);
  const float extra = (float)(2048 - send);
#pragma unroll
  for (int ni = 0; ni < 8; ++ni) {
    float sv = sp[(ni << 4) + l15];
#pragma unroll
    for (int j = 0; j < 4; ++j) oacc[ni][j] += sv;
  }

  // deferred ell reduction (within each 16-lane row group), then normalize
#pragma unroll
  for (int j = 0; j < 4; ++j) {
    float r = ell[j];
    r += __shfl_xor(r, 1, 64);
    r += __shfl_xor(r, 2, 64);
    r += __shfl_xor(r, 4, 64);
    r += __shfl_xor(r, 8, 64);
    float inv = 1.0f / (r + extra);
    int t = t0 + rb + j;
    unsigned short* op = O + qkbase + (size_t)t * 2048;
#pragma unroll
    for (int ni = 0; ni < 8; ++ni)
      op[(ni << 4) + l15] = f2bf(oacc[ni][j] * inv);
  }
}

// ---------------------------------------------------------------------------
// launch
// ---------------------------------------------------------------------------
extern "C" void kernel_launch(void* const* d_in, const int* in_sizes, int n_in,
                              void* d_out, int out_size, void* d_ws, size_t ws_size,
                              hipStream_t stream) {
  (void)in_sizes; (void)n_in; (void)out_size; (void)ws_size;
  const float* x  = (const float*)d_in[0];
  const float* Wq = (const float*)d_in[1];
  const float* Wk = (const float*)d_in[2];
  const float* Wv = (const float*)d_in[3];
  const float* Wo = (const float*)d_in[4];
  float* out = (float*)d_out;

  char* ws = (char*)d_ws;
  unsigned short* Xb  = (unsigned short*)(ws);                        // 16 MiB (reused as O)
  unsigned short* Wqt = (unsigned short*)(ws + 16777216);             // 8 MiB (reused as Suf)
  unsigned short* Wkt = (unsigned short*)(ws + 16777216 + 8388608);
  unsigned short* Wvt = (unsigned short*)(ws + 16777216 + 2 * 8388608);
  unsigned short* Wot = (unsigned short*)(ws + 16777216 + 3 * 8388608);
  unsigned short* Qb  = (unsigned short*)(ws + 50331648);             // 16 MiB
  unsigned short* Kb  = (unsigned short*)(ws + 67108864);             // 16 MiB
  unsigned short* Vt  = (unsigned short*)(ws + 83886080);             // 16 MiB
  unsigned short* Ob  = Xb;          // X dead after the QKV projection
  float*          Suf = (float*)Wqt; // W^T dead after the QKV projection

  cast_x_kernel<<<8192, 256, 0, stream>>>(x, Xb);
  {
    dim3 tb(32, 8), tg(64, 64, 4);
    transpose_w4_kernel<<<tg, tb, 0, stream>>>(Wq, Wk, Wv, Wo, Wqt, Wkt, Wvt, Wot);
  }
  // fused QKV projection: Bt = [Wqt|Wkt|Wvt] (contiguous), N=6144
  gemm_qkv2<<<512, 512, 0, stream>>>(Xb, Wqt, Qb, Kb, Vt);

  vsuf_kernel<<<1024, 256, 0, stream>>>(Vt, Suf);

  attn_kernel<<<1024, 256, 0, stream>>>(Qb, Kb, Vt, Suf, Ob);

  gemm_wo<<<512, 256, 0, stream>>>(Ob, Wot, out);
}